// Round 17
// baseline (504.688 us; speedup 1.0000x reference)
//
#include <hip/hip_runtime.h>
#include <hip/hip_bf16.h>

#define B_SZ 4
#define L_SZ 512
#define D_MODEL 256
#define D_INNER 512
#define D_STATE 16
#define DT_RANK 16
#define N_LAYERS 6
#define BL (B_SZ * L_SZ)   // 2048 token rows

typedef __bf16 bf16_t;
typedef __bf16 bf16x8 __attribute__((ext_vector_type(8)));
typedef __bf16 bf16x4 __attribute__((ext_vector_type(4)));
typedef float  f32x4  __attribute__((ext_vector_type(4)));

// All-reduce over the 16-lane DPP row via rotate-add.
__device__ __forceinline__ float row_allreduce16(float x)
{
    int v;
    v = __builtin_amdgcn_mov_dpp(__float_as_int(x), 0x121, 0xf, 0xf, true);
    x += __int_as_float(v);
    v = __builtin_amdgcn_mov_dpp(__float_as_int(x), 0x122, 0xf, 0xf, true);
    x += __int_as_float(v);
    v = __builtin_amdgcn_mov_dpp(__float_as_int(x), 0x124, 0xf, 0xf, true);
    x += __int_as_float(v);
    v = __builtin_amdgcn_mov_dpp(__float_as_int(x), 0x128, 0xf, 0xf, true);
    x += __int_as_float(v);
    return x;
}

// ---------------------------------------------------------------------------
// fp32 -> bf16 cast of the three weight tensors in one dispatch.
// ---------------------------------------------------------------------------
__global__ __launch_bounds__(256) void cast3_kernel(
    const float* __restrict__ s0, const float* __restrict__ s1,
    const float* __restrict__ s2, bf16_t* __restrict__ dst,
    int n0, int n1, int n2)
{
    int i = blockIdx.x * 256 + threadIdx.x;
    const float* s; int off;
    if (i < n0)            { s = s0; off = i; }
    else if (i < n0 + n1)  { s = s1; off = i - n0; }
    else if (i < n0+n1+n2) { s = s2; off = i - n0 - n1; }
    else return;
    const float4 v = *(const float4*)(s + (size_t)off * 4);
    bf16x4 o;
    o[0] = (bf16_t)v.x; o[1] = (bf16_t)v.y;
    o[2] = (bf16_t)v.z; o[3] = (bf16_t)v.w;
    *(bf16x4*)(dst + (size_t)i * 4) = o;
}

// ---------------------------------------------------------------------------
// RMSNorm -> bf16. Used ONCE (layer 0 input); later layers get xn from the
// W_out epilogue.
// ---------------------------------------------------------------------------
__global__ __launch_bounds__(256) void rmsnorm_kernel(
    const float* __restrict__ x, const float* __restrict__ w,
    bf16_t* __restrict__ o)
{
    int row  = blockIdx.x * 4 + (threadIdx.x >> 6);
    int lane = threadIdx.x & 63;
    const float4 v = *(const float4*)(x + (size_t)row * D_MODEL + lane * 4);
    float ss = v.x * v.x + v.y * v.y + v.z * v.z + v.w * v.w;
    #pragma unroll
    for (int off = 32; off; off >>= 1) ss += __shfl_xor(ss, off);
    float rs = rsqrtf(ss * (1.f / D_MODEL) + 1e-5f);
    const float4 wv = *(const float4*)(w + lane * 4);
    bf16x4 ov;
    ov[0] = (bf16_t)(v.x * rs * wv.x);
    ov[1] = (bf16_t)(v.y * rs * wv.y);
    ov[2] = (bf16_t)(v.z * rs * wv.z);
    ov[3] = (bf16_t)(v.w * rs * wv.w);
    *(bf16x4*)(o + (size_t)row * D_MODEL + lane * 4) = ov;
}

// ---------------------------------------------------------------------------
// bf16 MFMA NT GEMM with ZSPLIT epilogue (W_in).
// ---------------------------------------------------------------------------
template<int WM, int WN, int TM_T, int TN_T>
__global__ __launch_bounds__(64 * WM * WN) void gemm_win(
    const bf16_t* __restrict__ A, int lda,
    const bf16_t* __restrict__ Bw, int ldb,
    const float* __restrict__ bias,
    float* __restrict__ C, int ldc,
    float* __restrict__ Z,
    int K)
{
    constexpr int BK = 64;
    constexpr int BM = WM * TM_T * 16;
    constexpr int BN = WN * TN_T * 16;
    constexpr int NT = 64 * WM * WN;
    constexpr int LDK = BK + 8;
    __shared__ bf16_t As[BM][LDK];
    __shared__ bf16_t Bs[BN][LDK];

    const int tid  = threadIdx.x;
    const int wave = tid >> 6, lane = tid & 63;
    const int wm = wave / WN, wn = wave % WN;
    const int lm = lane & 15, quad = lane >> 4;
    const int m0 = blockIdx.y * BM, n0 = blockIdx.x * BN;

    f32x4 acc[TM_T][TN_T] = {};

    for (int k0 = 0; k0 < K; k0 += BK) {
        #pragma unroll
        for (int i = tid; i < BM * (BK / 8); i += NT) {
            int r = i >> 3, c8 = i & 7;
            *(bf16x8*)&As[r][c8 * 8] =
                *(const bf16x8*)(A + (size_t)(m0 + r) * lda + k0 + c8 * 8);
        }
        #pragma unroll
        for (int i = tid; i < BN * (BK / 8); i += NT) {
            int r = i >> 3, c8 = i & 7;
            *(bf16x8*)&Bs[r][c8 * 8] =
                *(const bf16x8*)(Bw + (size_t)(n0 + r) * ldb + k0 + c8 * 8);
        }
        __syncthreads();
        #pragma unroll
        for (int ks = 0; ks < BK / 32; ++ks) {
            bf16x8 af[TM_T], bfr[TN_T];
            #pragma unroll
            for (int i = 0; i < TM_T; ++i)
                af[i] = *(const bf16x8*)&As[wm * TM_T * 16 + i * 16 + lm][ks * 32 + quad * 8];
            #pragma unroll
            for (int j = 0; j < TN_T; ++j)
                bfr[j] = *(const bf16x8*)&Bs[wn * TN_T * 16 + j * 16 + lm][ks * 32 + quad * 8];
            #pragma unroll
            for (int i = 0; i < TM_T; ++i)
                #pragma unroll
                for (int j = 0; j < TN_T; ++j)
                    acc[i][j] = __builtin_amdgcn_mfma_f32_16x16x32_bf16(
                        af[i], bfr[j], acc[i][j], 0, 0, 0);
        }
        __syncthreads();
    }

    if (n0 >= D_INNER) {
        // z half: bias + silu, transposed float4 stores into Z (d-major)
        #pragma unroll
        for (int i = 0; i < TM_T; ++i) {
            int rowbase = m0 + wm * TM_T * 16 + i * 16 + quad * 4;
            #pragma unroll
            for (int j = 0; j < TN_T; ++j) {
                int col = n0 + wn * TN_T * 16 + j * 16 + lm;
                float4 o;
                #pragma unroll
                for (int r = 0; r < 4; ++r) {
                    float v = acc[i][j][r] + bias[col];
                    ((float*)&o)[r] = v / (1.f + __expf(-v));
                }
                *(float4*)(Z + (size_t)(col - D_INNER) * BL + rowbase) = o;
            }
        }
        return;
    }

    #pragma unroll
    for (int i = 0; i < TM_T; ++i) {
        #pragma unroll
        for (int j = 0; j < TN_T; ++j) {
            int col = n0 + wn * TN_T * 16 + j * 16 + lm;
            #pragma unroll
            for (int r = 0; r < 4; ++r) {
                int rowm = m0 + wm * TM_T * 16 + i * 16 + quad * 4 + r;
                C[(size_t)rowm * ldc + col] = acc[i][j][r] + bias[col];
            }
        }
    }
}

// ---------------------------------------------------------------------------
// Fused W_out GEMM + residual + (next-layer) RMSNorm.
// BM=16 rows x BN=256 (full row) per block; grid=128 blocks, 4 waves (512
// waves total, same as the old W_out). A (y, 16 rows) staged full-K once;
// K-loop stages only B. Epilogue: val = acc + bias + residual -> out fp32 +
// LDS tile; then per-row ss via 16-lane DPP allreduce (each row lives in one
// wave), scale by rsqrt*nw -> xn_bf for the next layer. NORM=0 on the last
// layer skips the norm phase.
// ---------------------------------------------------------------------------
template<int NORM>
__global__ __launch_bounds__(256) void wout_norm_kernel(
    const bf16_t* __restrict__ A,     // y_bf (BL, 512)
    const bf16_t* __restrict__ Bw,    // Wo_bf (256, 512)
    const float* __restrict__ bias,   // (256)
    const float* __restrict__ R,      // xcur (BL, 256)
    const float* __restrict__ nw,     // norm_w of NEXT layer (256)
    float* __restrict__ out,          // (BL, 256)
    bf16_t* __restrict__ xn)          // (BL, 256) bf16, if NORM
{
    constexpr int K = 512, BK = 64;
    __shared__ bf16_t As[16][K + 8];      // 16.3 KB, full-K A
    __shared__ bf16_t Bs[256][BK + 8];    // 36 KB
    __shared__ float  ot[16][260];        // 16.6 KB out tile

    const int tid  = threadIdx.x;
    const int wn   = tid >> 6;            // wave = col band
    const int lane = tid & 63;
    const int lm = lane & 15, quad = lane >> 4;
    const int m0 = blockIdx.x * 16;

    // stage A full-K: 16 rows x 64 chunks of 8
    #pragma unroll
    for (int i = tid; i < 16 * (K / 8); i += 256) {
        int r = i >> 6, c8 = i & 63;
        *(bf16x8*)&As[r][c8 * 8] =
            *(const bf16x8*)(A + (size_t)(m0 + r) * K + c8 * 8);
    }

    f32x4 acc[4] = {};
    for (int k0 = 0; k0 < K; k0 += BK) {
        #pragma unroll
        for (int i = tid; i < 256 * (BK / 8); i += 256) {
            int r = i >> 3, c8 = i & 7;
            *(bf16x8*)&Bs[r][c8 * 8] =
                *(const bf16x8*)(Bw + (size_t)r * K + k0 + c8 * 8);
        }
        __syncthreads();   // first iter also covers As
        #pragma unroll
        for (int ks = 0; ks < 2; ++ks) {
            bf16x8 af = *(const bf16x8*)&As[lm][k0 + ks * 32 + quad * 8];
            #pragma unroll
            for (int j = 0; j < 4; ++j) {
                bf16x8 bfr = *(const bf16x8*)&Bs[wn * 64 + j * 16 + lm][ks * 32 + quad * 8];
                acc[j] = __builtin_amdgcn_mfma_f32_16x16x32_bf16(af, bfr, acc[j], 0, 0, 0);
            }
        }
        __syncthreads();
    }

    // epilogue: bias + residual -> out (fp32) + LDS tile
    #pragma unroll
    for (int j = 0; j < 4; ++j) {
        int col = wn * 64 + j * 16 + lm;
        float bv = bias[col];
        #pragma unroll
        for (int r = 0; r < 4; ++r) {
            int row = quad * 4 + r;
            float v = acc[j][r] + bv + R[(size_t)(m0 + row) * D_MODEL + col];
            out[(size_t)(m0 + row) * D_MODEL + col] = v;
            ot[row][col] = v;
        }
    }
    if (NORM) {
        __syncthreads();
        // norm: thread = (row = tid>>4, 16-col chunk = (tid&15)*16)
        int row = tid >> 4, c0 = (tid & 15) * 16;
        float ss = 0.f;
        #pragma unroll
        for (int k = 0; k < 16; ++k) {
            float v = ot[row][c0 + k];
            ss += v * v;
        }
        ss = row_allreduce16(ss);   // row spans exactly lanes (row%4)*16..+15
        float rs = rsqrtf(ss * (1.f / D_MODEL) + 1e-5f);
        bf16x8 o0, o1;
        #pragma unroll
        for (int k = 0; k < 8; ++k) {
            o0[k] = (bf16_t)(ot[row][c0 + k]     * rs * nw[c0 + k]);
            o1[k] = (bf16_t)(ot[row][c0 + 8 + k] * rs * nw[c0 + 8 + k]);
        }
        *(bf16x8*)(xn + (size_t)(m0 + row) * D_MODEL + c0)     = o0;
        *(bf16x8*)(xn + (size_t)(m0 + row) * D_MODEL + c0 + 8) = o1;
    }
}

// ---------------------------------------------------------------------------
// Fused conv+silu + W_x GEMM (wave-parallel K-split, 512 waves, 128 blocks).
// ---------------------------------------------------------------------------
__global__ __launch_bounds__(256) void wx_conv_kernel(
    const float* __restrict__ xzx,    // (BL, 512) x half, m-major
    const float* __restrict__ cw,     // (512, 4)
    const bf16_t* __restrict__ Bw,    // Wx_bf (48, 512)
    float* __restrict__ uT,           // (512, BL)
    float* __restrict__ xdbcT)        // (48, BL)
{
    constexpr int K = 512;
    __shared__ float  xs[19][516];    // xz rows m0-3..m0+15
    __shared__ bf16_t us[16][520];    // u tile, [m][k], bf16
    __shared__ f32x4  part[4][3][64];

    const int tid  = threadIdx.x;
    const int wave = tid >> 6, lane = tid & 63;
    const int lm = lane & 15, quad = lane >> 4;
    const int m0 = blockIdx.x * 16;

    for (int q = tid; q < 19 * 128; q += 256) {
        int rx = q >> 7, c4 = (q & 127) * 4;
        int mr = m0 - 3 + rx;
        float4 v = make_float4(0.f, 0.f, 0.f, 0.f);
        if (mr >= 0) v = *(const float4*)(xzx + (size_t)mr * K + c4);
        *(float4*)&xs[rx][c4] = v;
    }
    __syncthreads();

    #pragma unroll
    for (int it = 0; it < 8; ++it) {
        int item = tid + it * 256;
        int d = item >> 2, rg = item & 3;
        const float4 wv = *(const float4*)(cw + d * 4);
        float4 o;
        #pragma unroll
        for (int e = 0; e < 4; ++e) {
            int ro = rg * 4 + e;
            int t  = (m0 + ro) & (L_SZ - 1);
            float a = wv.w * xs[ro + 3][d];
            if (t >= 1) a += wv.z * xs[ro + 2][d];
            if (t >= 2) a += wv.y * xs[ro + 1][d];
            if (t >= 3) a += wv.x * xs[ro + 0][d];
            a = a / (1.f + __expf(-a));
            ((float*)&o)[e] = a;
            us[ro][d] = (bf16_t)a;
        }
        *(float4*)(uT + (size_t)d * BL + m0 + rg * 4) = o;
    }
    __syncthreads();

    f32x4 acc[3] = {};
    const int kb = wave * 128 + quad * 8;
    #pragma unroll
    for (int ks = 0; ks < 4; ++ks) {
        int k0 = kb + ks * 32;
        bf16x8 af = *(const bf16x8*)&us[lm][k0];
        #pragma unroll
        for (int j = 0; j < 3; ++j) {
            bf16x8 bfr = *(const bf16x8*)(Bw + (size_t)(j * 16 + lm) * K + k0);
            acc[j] = __builtin_amdgcn_mfma_f32_16x16x32_bf16(af, bfr, acc[j], 0, 0, 0);
        }
    }
    #pragma unroll
    for (int j = 0; j < 3; ++j) part[wave][j][lane] = acc[j];
    __syncthreads();

    if (tid < 192) {
        int j = tid >> 6, l = tid & 63;
        f32x4 s = part[0][j][l];
        s += part[1][j][l];
        s += part[2][j][l];
        s += part[3][j][l];
        int col = j * 16 + (l & 15);
        float4 v = make_float4(s[0], s[1], s[2], s[3]);
        *(float4*)(xdbcT + (size_t)col * BL + m0 + (l >> 4) * 4) = v;
    }
}

// ---------------------------------------------------------------------------
// Selective scan v7 (R16 proven): single-recurrence + in-scan delta.
// ---------------------------------------------------------------------------
__global__ __launch_bounds__(1024, 4) void scan_kernel(
    const float* __restrict__ xdbcT,  // (48, BL): [dt | B | C]
    const float* __restrict__ uT,     // (512, BL)
    const float* __restrict__ szT,    // (512, BL)
    const float* __restrict__ dt_w,   // (512, 16)
    const float* __restrict__ dt_b,   // (512)
    const float* __restrict__ A_log,  // (512, 16)
    const float* __restrict__ Dv,     // (512)
    bf16_t* __restrict__ y)           // (BL, 512) bf16
{
    constexpr int TC = 32;
    constexpr int NW = L_SZ / TC;     // 16 waves

    int blk  = blockIdx.x;            // 512 blocks: b*128 + dg
    int b    = blk >> 7;
    int dg   = blk & 127;
    int wave = threadIdx.x >> 6;
    int lane = threadIdx.x & 63;
    int d    = dg * 4 + (lane >> 4);
    int n    = lane & 15;

    __shared__ float lds_Ap[NW][64];
    __shared__ float lds_he[NW][64];

    float Adn = -__expf(A_log[d * D_STATE + n]);
    float Dd  = Dv[d];
    int r0 = b * L_SZ + wave * TC;

    const float* Brow = xdbcT  + (size_t)(DT_RANK + n) * BL;
    const float* Crow = xdbcT  + (size_t)(DT_RANK + D_STATE + n) * BL;
    const float* urow = uT     + (size_t)d * BL;
    const float* zrow = szT    + (size_t)d * BL;

    // ---- in-scan delta: lane n computes delta(t=r0+n), delta(t=r0+16+n) ----
    float myd[2];
    {
        float w16[16];
        #pragma unroll
        for (int k4 = 0; k4 < 4; ++k4) {
            float4 wv = *(const float4*)(dt_w + (size_t)d * 16 + k4 * 4);
            w16[k4*4+0] = wv.x; w16[k4*4+1] = wv.y;
            w16[k4*4+2] = wv.z; w16[k4*4+3] = wv.w;
        }
        float bdt = dt_b[d];
        #pragma unroll
        for (int g = 0; g < 2; ++g) {
            int t = r0 + g * 16 + n;    // wave-coalesced over n
            float a = bdt;
            #pragma unroll
            for (int k = 0; k < 16; ++k)
                a += xdbcT[(size_t)k * BL + t] * w16[k];
            myd[g] = (a > 20.f) ? a : __logf(1.f + __expf(a));
        }
    }
    const int sbase = lane & 48;      // d-group base lane for shfl gather

    // ---- pass 1: local scan, saving hl[t] and running product P[t] ----
    float hl[TC], Pl[TC];
    float h = 0.f, P = 1.f;
    #pragma unroll
    for (int g = 0; g < 2; ++g) {
        #pragma unroll
        for (int j4 = 0; j4 < 4; ++j4) {
            int rb = r0 + g * 16 + j4 * 4;
            f32x4 Bv = *(const f32x4*)(Brow + rb);
            f32x4 uv = *(const f32x4*)(urow + rb);
            float dA[4], dBu[4];
            #pragma unroll
            for (int k = 0; k < 4; ++k) {
                float dlj = __shfl(myd[g], sbase | (j4 * 4 + k));
                dA[k]  = __expf(dlj * Adn);
                dBu[k] = dlj * uv[k] * Bv[k];
            }
            #pragma unroll
            for (int k = 0; k < 4; ++k) {
                int t = g * 16 + j4 * 4 + k;
                h = dA[k] * h + dBu[k];
                P *= dA[k];
                hl[t] = h;
                Pl[t] = P;
            }
        }
    }
    lds_Ap[wave][lane] = P;
    lds_he[wave][lane] = h;
    __syncthreads();

    float H = 0.f;
    for (int j = 0; j < wave; ++j)
        H = lds_Ap[j][lane] * H + lds_he[j][lane];

    // ---- pass 2: fully parallel reconstruction, C stream only ----
    #pragma unroll
    for (int t0 = 0; t0 < TC; t0 += 16) {
        float py[16];
        #pragma unroll
        for (int j4 = 0; j4 < 4; ++j4) {
            int rb = r0 + t0 + j4 * 4;
            f32x4 Cc = *(const f32x4*)(Crow + rb);
            #pragma unroll
            for (int k = 0; k < 4; ++k) {
                int t = t0 + j4 * 4 + k;
                py[j4*4+k] = (hl[t] + Pl[t] * H) * Cc[k];
            }
        }
        #pragma unroll
        for (int j = 0; j < 16; ++j)
            py[j] = row_allreduce16(py[j]);
        if (n == 0) {
            #pragma unroll
            for (int j4 = 0; j4 < 4; ++j4) {
                int rb = r0 + t0 + j4 * 4;
                f32x4 uv = *(const f32x4*)(urow + rb);
                f32x4 sz = *(const f32x4*)(zrow + rb);
                #pragma unroll
                for (int k = 0; k < 4; ++k) {
                    int row = rb + k;
                    y[(size_t)row * D_INNER + d] =
                        (bf16_t)((py[j4*4+k] + uv[k] * Dd) * sz[k]);
                }
            }
        }
    }
}

// ---------------------------------------------------------------------------
extern "C" void kernel_launch(void* const* d_in, const int* in_sizes, int n_in,
                              void* d_out, int out_size, void* d_ws, size_t ws_size,
                              hipStream_t stream)
{
    const float* x_in   = (const float*)d_in[0];
    const float* norm_w = (const float*)d_in[1];
    const float* W_in   = (const float*)d_in[2];
    const float* b_in   = (const float*)d_in[3];
    const float* conv_w = (const float*)d_in[4];
    const float* W_x    = (const float*)d_in[5];
    const float* dt_w   = (const float*)d_in[6];
    const float* dt_b   = (const float*)d_in[7];
    const float* A_log  = (const float*)d_in[8];
    const float* Dv     = (const float*)d_in[9];
    const float* W_out  = (const float*)d_in[10];
    const float* b_out  = (const float*)d_in[11];
    float* out = (float*)d_out;

    // fp32 scratch
    float* ws     = (float*)d_ws;
    float* xz     = ws;                        // 2048*512 (x half only)
    float* uT     = xz     + BL * D_INNER;     // 512*2048
    float* szT    = uT     + D_INNER * BL;     // 512*2048
    float* xdbcT  = szT    + D_INNER * BL;     // 48*2048
    // bf16 scratch
    bf16_t* bws   = (bf16_t*)(xdbcT + 48 * BL);
    bf16_t* xn_bf = bws;                       // 2048*256
    bf16_t* y_bf  = xn_bf + BL * D_MODEL;      // 2048*512
    bf16_t* Wi_bf = y_bf  + BL * D_INNER;      // 6*1024*256
    bf16_t* Wx_bf = Wi_bf + N_LAYERS * 2 * D_INNER * D_MODEL;
    bf16_t* Wo_bf = Wx_bf + N_LAYERS * 48 * D_INNER;

    // ---- weight casts, one dispatch (dsts contiguous: Wi|Wx|Wo) ----
    {
        int n0 = N_LAYERS * 2 * D_INNER * D_MODEL / 4;
        int n1 = N_LAYERS * 48 * D_INNER / 4;
        int n2 = N_LAYERS * D_MODEL * D_INNER / 4;
        cast3_kernel<<<(n0 + n1 + n2 + 255) / 256, 256, 0, stream>>>(
            W_in, W_x, W_out, Wi_bf, n0, n1, n2);
    }

    // layer-0 input norm (later layers get xn from the W_out epilogue)
    rmsnorm_kernel<<<BL / 4, 256, 0, stream>>>(x_in, norm_w, xn_bf);

    for (int i = 0; i < N_LAYERS; ++i) {
        const float* xcur = (i == 0) ? x_in : out;

        // xz(x half) + szT(z half, silu, transposed) = xn @ W_in^T + b_in
        gemm_win<2, 2, 2, 2><<<dim3(1024 / 64, 2048 / 64), 256, 0, stream>>>(
            xn_bf, D_MODEL, Wi_bf + (size_t)i * 2 * D_INNER * D_MODEL, D_MODEL,
            b_in + i * 2 * D_INNER, xz, D_INNER, szT, D_MODEL);

        // conv+silu fused with W_x GEMM: uT + xdbcT
        wx_conv_kernel<<<BL / 16, 256, 0, stream>>>(
            xz, conv_w + i * D_INNER * 4,
            Wx_bf + (size_t)i * 48 * D_INNER, uT, xdbcT);

        // scan with in-scan delta
        scan_kernel<<<512, 1024, 0, stream>>>(
            xdbcT, uT, szT,
            dt_w + (size_t)i * D_INNER * DT_RANK, dt_b + i * D_INNER,
            A_log + (size_t)i * D_INNER * D_STATE, Dv + i * D_INNER, y_bf);

        // out = xcur + y @ W_out^T + b_out; fused next-layer rmsnorm -> xn_bf
        if (i < N_LAYERS - 1) {
            wout_norm_kernel<1><<<BL / 16, 256, 0, stream>>>(
                y_bf, Wo_bf + (size_t)i * D_MODEL * D_INNER,
                b_out + i * D_MODEL, xcur, norm_w + (i + 1) * D_MODEL,
                out, xn_bf);
        } else {
            wout_norm_kernel<0><<<BL / 16, 256, 0, stream>>>(
                y_bf, Wo_bf + (size_t)i * D_MODEL * D_INNER,
                b_out + i * D_MODEL, xcur, nullptr, out, nullptr);
        }
    }
}

// Round 18
// 483.669 us; speedup vs baseline: 1.0435x; 1.0435x over previous
//
#include <hip/hip_runtime.h>
#include <hip/hip_bf16.h>

#define B_SZ 4
#define L_SZ 512
#define D_MODEL 256
#define D_INNER 512
#define D_STATE 16
#define DT_RANK 16
#define N_LAYERS 6
#define BL (B_SZ * L_SZ)   // 2048 token rows

typedef __bf16 bf16_t;
typedef __bf16 bf16x8 __attribute__((ext_vector_type(8)));
typedef __bf16 bf16x4 __attribute__((ext_vector_type(4)));
typedef float  f32x4  __attribute__((ext_vector_type(4)));

// All-reduce over the 16-lane DPP row (our n-group) via rotate-add.
__device__ __forceinline__ float row_allreduce16(float x)
{
    int v;
    v = __builtin_amdgcn_mov_dpp(__float_as_int(x), 0x121, 0xf, 0xf, true);
    x += __int_as_float(v);
    v = __builtin_amdgcn_mov_dpp(__float_as_int(x), 0x122, 0xf, 0xf, true);
    x += __int_as_float(v);
    v = __builtin_amdgcn_mov_dpp(__float_as_int(x), 0x124, 0xf, 0xf, true);
    x += __int_as_float(v);
    v = __builtin_amdgcn_mov_dpp(__float_as_int(x), 0x128, 0xf, 0xf, true);
    x += __int_as_float(v);
    return x;
}

// ---------------------------------------------------------------------------
// fp32 -> bf16 cast of the three weight tensors in one dispatch.
// ---------------------------------------------------------------------------
__global__ __launch_bounds__(256) void cast3_kernel(
    const float* __restrict__ s0, const float* __restrict__ s1,
    const float* __restrict__ s2, bf16_t* __restrict__ dst,
    int n0, int n1, int n2)
{
    int i = blockIdx.x * 256 + threadIdx.x;
    const float* s; int off;
    if (i < n0)            { s = s0; off = i; }
    else if (i < n0 + n1)  { s = s1; off = i - n0; }
    else if (i < n0+n1+n2) { s = s2; off = i - n0 - n1; }
    else return;
    const float4 v = *(const float4*)(s + (size_t)off * 4);
    bf16x4 o;
    o[0] = (bf16_t)v.x; o[1] = (bf16_t)v.y;
    o[2] = (bf16_t)v.z; o[3] = (bf16_t)v.w;
    *(bf16x4*)(dst + (size_t)i * 4) = o;
}

// ---------------------------------------------------------------------------
// RMSNorm -> bf16 output. One wave per row of 256; 4 rows per block.
// (R15/R17 showed fusing this elsewhere loses; keep standalone.)
// ---------------------------------------------------------------------------
__global__ __launch_bounds__(256) void rmsnorm_kernel(
    const float* __restrict__ x, const float* __restrict__ w,
    bf16_t* __restrict__ o)
{
    int row  = blockIdx.x * 4 + (threadIdx.x >> 6);
    int lane = threadIdx.x & 63;
    const float4 v = *(const float4*)(x + (size_t)row * D_MODEL + lane * 4);
    float ss = v.x * v.x + v.y * v.y + v.z * v.z + v.w * v.w;
    #pragma unroll
    for (int off = 32; off; off >>= 1) ss += __shfl_xor(ss, off);
    float rs = rsqrtf(ss * (1.f / D_MODEL) + 1e-5f);
    const float4 wv = *(const float4*)(w + lane * 4);
    bf16x4 ov;
    ov[0] = (bf16_t)(v.x * rs * wv.x);
    ov[1] = (bf16_t)(v.y * rs * wv.y);
    ov[2] = (bf16_t)(v.z * rs * wv.z);
    ov[3] = (bf16_t)(v.w * rs * wv.w);
    *(bf16x4*)(o + (size_t)row * D_MODEL + lane * 4) = ov;
}

// ---------------------------------------------------------------------------
// W_in GEMM (K=256) with full-K A staging + ZSPLIT epilogue.
// BM=BN=64, 4 waves; A staged once (64 x 264 bf16, 33.8 KB), K-loop stages
// only B. Cols >= D_INNER: bias+silu -> transposed float4 stores into Z.
// ---------------------------------------------------------------------------
__global__ __launch_bounds__(256) void win_kernel(
    const bf16_t* __restrict__ A,      // xn_bf (BL, 256)
    const bf16_t* __restrict__ Bw,     // Wi_bf (1024, 256)
    const float* __restrict__ bias,    // (1024)
    float* __restrict__ C,             // xz x-half (BL, 512)
    float* __restrict__ Z)             // szT (512, BL)
{
    constexpr int K = 256, BK = 64;
    __shared__ bf16_t As[64][K + 8];   // full-K A
    __shared__ bf16_t Bs[64][BK + 8];

    const int tid  = threadIdx.x;
    const int wave = tid >> 6, lane = tid & 63;
    const int wm = wave >> 1, wn = wave & 1;
    const int lm = lane & 15, quad = lane >> 4;
    const int m0 = blockIdx.y * 64, n0 = blockIdx.x * 64;

    // stage A full-K: 64 rows x 32 chunks of 8
    #pragma unroll
    for (int i = tid; i < 64 * (K / 8); i += 256) {
        int r = i >> 5, c8 = i & 31;
        *(bf16x8*)&As[r][c8 * 8] =
            *(const bf16x8*)(A + (size_t)(m0 + r) * K + c8 * 8);
    }

    f32x4 acc[2][2] = {};
    for (int k0 = 0; k0 < K; k0 += BK) {
        #pragma unroll
        for (int i = tid; i < 64 * (BK / 8); i += 256) {
            int r = i >> 3, c8 = i & 7;
            *(bf16x8*)&Bs[r][c8 * 8] =
                *(const bf16x8*)(Bw + (size_t)(n0 + r) * K + k0 + c8 * 8);
        }
        __syncthreads();   // first barrier also covers the As staging
        #pragma unroll
        for (int ks = 0; ks < 2; ++ks) {
            bf16x8 af[2], bfr[2];
            #pragma unroll
            for (int i = 0; i < 2; ++i)
                af[i] = *(const bf16x8*)&As[wm * 32 + i * 16 + lm][k0 + ks * 32 + quad * 8];
            #pragma unroll
            for (int j = 0; j < 2; ++j)
                bfr[j] = *(const bf16x8*)&Bs[wn * 32 + j * 16 + lm][ks * 32 + quad * 8];
            #pragma unroll
            for (int i = 0; i < 2; ++i)
                #pragma unroll
                for (int j = 0; j < 2; ++j)
                    acc[i][j] = __builtin_amdgcn_mfma_f32_16x16x32_bf16(
                        af[i], bfr[j], acc[i][j], 0, 0, 0);
        }
        __syncthreads();
    }

    if (n0 >= D_INNER) {
        // z half: bias + silu, transposed float4 stores into Z (d-major)
        #pragma unroll
        for (int i = 0; i < 2; ++i) {
            int rowbase = m0 + wm * 32 + i * 16 + quad * 4;
            #pragma unroll
            for (int j = 0; j < 2; ++j) {
                int col = n0 + wn * 32 + j * 16 + lm;
                float4 o;
                #pragma unroll
                for (int r = 0; r < 4; ++r) {
                    float v = acc[i][j][r] + bias[col];
                    ((float*)&o)[r] = v / (1.f + __expf(-v));
                }
                *(float4*)(Z + (size_t)(col - D_INNER) * BL + rowbase) = o;
            }
        }
        return;
    }

    #pragma unroll
    for (int i = 0; i < 2; ++i) {
        #pragma unroll
        for (int j = 0; j < 2; ++j) {
            int col = n0 + wn * 32 + j * 16 + lm;
            #pragma unroll
            for (int r = 0; r < 4; ++r) {
                int rowm = m0 + wm * 32 + i * 16 + quad * 4 + r;
                C[(size_t)rowm * D_INNER + col] = acc[i][j][r] + bias[col];
            }
        }
    }
}

// ---------------------------------------------------------------------------
// bf16 MFMA NT GEMM (W_out): C = A @ B^T + bias + residual, fp32 out.
// R16-proven 64x64 tiling.
// ---------------------------------------------------------------------------
template<int WM, int WN, int TM_T, int TN_T>
__global__ __launch_bounds__(64 * WM * WN) void gemm_wout(
    const bf16_t* __restrict__ A, int lda,
    const bf16_t* __restrict__ Bw, int ldb,
    const float* __restrict__ bias,
    const float* __restrict__ R, int ldr,
    float* __restrict__ C, int ldc, int K)
{
    constexpr int BK = 64;
    constexpr int BM = WM * TM_T * 16;
    constexpr int BN = WN * TN_T * 16;
    constexpr int NT = 64 * WM * WN;
    constexpr int LDK = BK + 8;
    __shared__ bf16_t As[BM][LDK];
    __shared__ bf16_t Bs[BN][LDK];

    const int tid  = threadIdx.x;
    const int wave = tid >> 6, lane = tid & 63;
    const int wm = wave / WN, wn = wave % WN;
    const int lm = lane & 15, quad = lane >> 4;
    const int m0 = blockIdx.y * BM, n0 = blockIdx.x * BN;

    f32x4 acc[TM_T][TN_T] = {};

    for (int k0 = 0; k0 < K; k0 += BK) {
        #pragma unroll
        for (int i = tid; i < BM * (BK / 8); i += NT) {
            int r = i >> 3, c8 = i & 7;
            *(bf16x8*)&As[r][c8 * 8] =
                *(const bf16x8*)(A + (size_t)(m0 + r) * lda + k0 + c8 * 8);
        }
        #pragma unroll
        for (int i = tid; i < BN * (BK / 8); i += NT) {
            int r = i >> 3, c8 = i & 7;
            *(bf16x8*)&Bs[r][c8 * 8] =
                *(const bf16x8*)(Bw + (size_t)(n0 + r) * ldb + k0 + c8 * 8);
        }
        __syncthreads();
        #pragma unroll
        for (int ks = 0; ks < BK / 32; ++ks) {
            bf16x8 af[TM_T], bfr[TN_T];
            #pragma unroll
            for (int i = 0; i < TM_T; ++i)
                af[i] = *(const bf16x8*)&As[wm * TM_T * 16 + i * 16 + lm][ks * 32 + quad * 8];
            #pragma unroll
            for (int j = 0; j < TN_T; ++j)
                bfr[j] = *(const bf16x8*)&Bs[wn * TN_T * 16 + j * 16 + lm][ks * 32 + quad * 8];
            #pragma unroll
            for (int i = 0; i < TM_T; ++i)
                #pragma unroll
                for (int j = 0; j < TN_T; ++j)
                    acc[i][j] = __builtin_amdgcn_mfma_f32_16x16x32_bf16(
                        af[i], bfr[j], acc[i][j], 0, 0, 0);
        }
        __syncthreads();
    }

    #pragma unroll
    for (int i = 0; i < TM_T; ++i) {
        #pragma unroll
        for (int j = 0; j < TN_T; ++j) {
            int col = n0 + wn * TN_T * 16 + j * 16 + lm;
            #pragma unroll
            for (int r = 0; r < 4; ++r) {
                int rowm = m0 + wm * TM_T * 16 + i * 16 + quad * 4 + r;
                C[(size_t)rowm * ldc + col] =
                    acc[i][j][r] + bias[col] + R[(size_t)rowm * ldr + col];
            }
        }
    }
}

// ---------------------------------------------------------------------------
// Fused conv+silu + W_x GEMM (wave-parallel K-split, 512 waves, 128 blocks).
// ---------------------------------------------------------------------------
__global__ __launch_bounds__(256) void wx_conv_kernel(
    const float* __restrict__ xzx,    // (BL, 512) x half, m-major
    const float* __restrict__ cw,     // (512, 4)
    const bf16_t* __restrict__ Bw,    // Wx_bf (48, 512)
    float* __restrict__ uT,           // (512, BL)
    float* __restrict__ xdbcT)        // (48, BL)
{
    constexpr int K = 512;
    __shared__ float  xs[19][516];    // xz rows m0-3..m0+15
    __shared__ bf16_t us[16][520];    // u tile, [m][k], bf16
    __shared__ f32x4  part[4][3][64];

    const int tid  = threadIdx.x;
    const int wave = tid >> 6, lane = tid & 63;
    const int lm = lane & 15, quad = lane >> 4;
    const int m0 = blockIdx.x * 16;

    for (int q = tid; q < 19 * 128; q += 256) {
        int rx = q >> 7, c4 = (q & 127) * 4;
        int mr = m0 - 3 + rx;
        float4 v = make_float4(0.f, 0.f, 0.f, 0.f);
        if (mr >= 0) v = *(const float4*)(xzx + (size_t)mr * K + c4);
        *(float4*)&xs[rx][c4] = v;
    }
    __syncthreads();

    #pragma unroll
    for (int it = 0; it < 8; ++it) {
        int item = tid + it * 256;
        int d = item >> 2, rg = item & 3;
        const float4 wv = *(const float4*)(cw + d * 4);
        float4 o;
        #pragma unroll
        for (int e = 0; e < 4; ++e) {
            int ro = rg * 4 + e;
            int t  = (m0 + ro) & (L_SZ - 1);
            float a = wv.w * xs[ro + 3][d];
            if (t >= 1) a += wv.z * xs[ro + 2][d];
            if (t >= 2) a += wv.y * xs[ro + 1][d];
            if (t >= 3) a += wv.x * xs[ro + 0][d];
            a = a / (1.f + __expf(-a));
            ((float*)&o)[e] = a;
            us[ro][d] = (bf16_t)a;
        }
        *(float4*)(uT + (size_t)d * BL + m0 + rg * 4) = o;
    }
    __syncthreads();

    f32x4 acc[3] = {};
    const int kb = wave * 128 + quad * 8;
    #pragma unroll
    for (int ks = 0; ks < 4; ++ks) {
        int k0 = kb + ks * 32;
        bf16x8 af = *(const bf16x8*)&us[lm][k0];
        #pragma unroll
        for (int j = 0; j < 3; ++j) {
            bf16x8 bfr = *(const bf16x8*)(Bw + (size_t)(j * 16 + lm) * K + k0);
            acc[j] = __builtin_amdgcn_mfma_f32_16x16x32_bf16(af, bfr, acc[j], 0, 0, 0);
        }
    }
    #pragma unroll
    for (int j = 0; j < 3; ++j) part[wave][j][lane] = acc[j];
    __syncthreads();

    if (tid < 192) {
        int j = tid >> 6, l = tid & 63;
        f32x4 s = part[0][j][l];
        s += part[1][j][l];
        s += part[2][j][l];
        s += part[3][j][l];
        int col = j * 16 + (l & 15);
        float4 v = make_float4(s[0], s[1], s[2], s[3]);
        *(float4*)(xdbcT + (size_t)col * BL + m0 + (l >> 4) * 4) = v;
    }
}

// ---------------------------------------------------------------------------
// Selective scan v7 (R16 proven): single-recurrence + in-scan delta.
// ---------------------------------------------------------------------------
__global__ __launch_bounds__(1024, 4) void scan_kernel(
    const float* __restrict__ xdbcT,  // (48, BL): [dt | B | C]
    const float* __restrict__ uT,     // (512, BL)
    const float* __restrict__ szT,    // (512, BL)
    const float* __restrict__ dt_w,   // (512, 16)
    const float* __restrict__ dt_b,   // (512)
    const float* __restrict__ A_log,  // (512, 16)
    const float* __restrict__ Dv,     // (512)
    bf16_t* __restrict__ y)           // (BL, 512) bf16
{
    constexpr int TC = 32;
    constexpr int NW = L_SZ / TC;     // 16 waves

    int blk  = blockIdx.x;            // 512 blocks: b*128 + dg
    int b    = blk >> 7;
    int dg   = blk & 127;
    int wave = threadIdx.x >> 6;
    int lane = threadIdx.x & 63;
    int d    = dg * 4 + (lane >> 4);
    int n    = lane & 15;

    __shared__ float lds_Ap[NW][64];
    __shared__ float lds_he[NW][64];

    float Adn = -__expf(A_log[d * D_STATE + n]);
    float Dd  = Dv[d];
    int r0 = b * L_SZ + wave * TC;

    const float* Brow = xdbcT  + (size_t)(DT_RANK + n) * BL;
    const float* Crow = xdbcT  + (size_t)(DT_RANK + D_STATE + n) * BL;
    const float* urow = uT     + (size_t)d * BL;
    const float* zrow = szT    + (size_t)d * BL;

    // ---- in-scan delta: lane n computes delta(t=r0+n), delta(t=r0+16+n) ----
    float myd[2];
    {
        float w16[16];
        #pragma unroll
        for (int k4 = 0; k4 < 4; ++k4) {
            float4 wv = *(const float4*)(dt_w + (size_t)d * 16 + k4 * 4);
            w16[k4*4+0] = wv.x; w16[k4*4+1] = wv.y;
            w16[k4*4+2] = wv.z; w16[k4*4+3] = wv.w;
        }
        float bdt = dt_b[d];
        #pragma unroll
        for (int g = 0; g < 2; ++g) {
            int t = r0 + g * 16 + n;    // wave-coalesced over n
            float a = bdt;
            #pragma unroll
            for (int k = 0; k < 16; ++k)
                a += xdbcT[(size_t)k * BL + t] * w16[k];
            myd[g] = (a > 20.f) ? a : __logf(1.f + __expf(a));
        }
    }
    const int sbase = lane & 48;      // d-group base lane for shfl gather

    // ---- pass 1: local scan, saving hl[t] and running product P[t] ----
    float hl[TC], Pl[TC];
    float h = 0.f, P = 1.f;
    #pragma unroll
    for (int g = 0; g < 2; ++g) {
        #pragma unroll
        for (int j4 = 0; j4 < 4; ++j4) {
            int rb = r0 + g * 16 + j4 * 4;
            f32x4 Bv = *(const f32x4*)(Brow + rb);
            f32x4 uv = *(const f32x4*)(urow + rb);
            float dA[4], dBu[4];
            #pragma unroll
            for (int k = 0; k < 4; ++k) {
                float dlj = __shfl(myd[g], sbase | (j4 * 4 + k));
                dA[k]  = __expf(dlj * Adn);
                dBu[k] = dlj * uv[k] * Bv[k];
            }
            #pragma unroll
            for (int k = 0; k < 4; ++k) {
                int t = g * 16 + j4 * 4 + k;
                h = dA[k] * h + dBu[k];
                P *= dA[k];
                hl[t] = h;
                Pl[t] = P;
            }
        }
    }
    lds_Ap[wave][lane] = P;
    lds_he[wave][lane] = h;
    __syncthreads();

    float H = 0.f;
    for (int j = 0; j < wave; ++j)
        H = lds_Ap[j][lane] * H + lds_he[j][lane];

    // ---- pass 2: fully parallel reconstruction, C stream only ----
    #pragma unroll
    for (int t0 = 0; t0 < TC; t0 += 16) {
        float py[16];
        #pragma unroll
        for (int j4 = 0; j4 < 4; ++j4) {
            int rb = r0 + t0 + j4 * 4;
            f32x4 Cc = *(const f32x4*)(Crow + rb);
            #pragma unroll
            for (int k = 0; k < 4; ++k) {
                int t = t0 + j4 * 4 + k;
                py[j4*4+k] = (hl[t] + Pl[t] * H) * Cc[k];
            }
        }
        #pragma unroll
        for (int j = 0; j < 16; ++j)
            py[j] = row_allreduce16(py[j]);
        if (n == 0) {
            #pragma unroll
            for (int j4 = 0; j4 < 4; ++j4) {
                int rb = r0 + t0 + j4 * 4;
                f32x4 uv = *(const f32x4*)(urow + rb);
                f32x4 sz = *(const f32x4*)(zrow + rb);
                #pragma unroll
                for (int k = 0; k < 4; ++k) {
                    int row = rb + k;
                    y[(size_t)row * D_INNER + d] =
                        (bf16_t)((py[j4*4+k] + uv[k] * Dd) * sz[k]);
                }
            }
        }
    }
}

// ---------------------------------------------------------------------------
extern "C" void kernel_launch(void* const* d_in, const int* in_sizes, int n_in,
                              void* d_out, int out_size, void* d_ws, size_t ws_size,
                              hipStream_t stream)
{
    const float* x_in   = (const float*)d_in[0];
    const float* norm_w = (const float*)d_in[1];
    const float* W_in   = (const float*)d_in[2];
    const float* b_in   = (const float*)d_in[3];
    const float* conv_w = (const float*)d_in[4];
    const float* W_x    = (const float*)d_in[5];
    const float* dt_w   = (const float*)d_in[6];
    const float* dt_b   = (const float*)d_in[7];
    const float* A_log  = (const float*)d_in[8];
    const float* Dv     = (const float*)d_in[9];
    const float* W_out  = (const float*)d_in[10];
    const float* b_out  = (const float*)d_in[11];
    float* out = (float*)d_out;

    // fp32 scratch
    float* ws     = (float*)d_ws;
    float* xz     = ws;                        // 2048*512 (x half only)
    float* uT     = xz     + BL * D_INNER;     // 512*2048
    float* szT    = uT     + D_INNER * BL;     // 512*2048
    float* xdbcT  = szT    + D_INNER * BL;     // 48*2048
    // bf16 scratch
    bf16_t* bws   = (bf16_t*)(xdbcT + 48 * BL);
    bf16_t* xn_bf = bws;                       // 2048*256
    bf16_t* y_bf  = xn_bf + BL * D_MODEL;      // 2048*512
    bf16_t* Wi_bf = y_bf  + BL * D_INNER;      // 6*1024*256
    bf16_t* Wx_bf = Wi_bf + N_LAYERS * 2 * D_INNER * D_MODEL;
    bf16_t* Wo_bf = Wx_bf + N_LAYERS * 48 * D_INNER;

    // ---- weight casts, one dispatch (dsts contiguous: Wi|Wx|Wo) ----
    {
        int n0 = N_LAYERS * 2 * D_INNER * D_MODEL / 4;
        int n1 = N_LAYERS * 48 * D_INNER / 4;
        int n2 = N_LAYERS * D_MODEL * D_INNER / 4;
        cast3_kernel<<<(n0 + n1 + n2 + 255) / 256, 256, 0, stream>>>(
            W_in, W_x, W_out, Wi_bf, n0, n1, n2);
    }

    for (int i = 0; i < N_LAYERS; ++i) {
        const float* xcur = (i == 0) ? x_in : out;

        rmsnorm_kernel<<<BL / 4, 256, 0, stream>>>(xcur, norm_w + i * D_MODEL, xn_bf);

        // xz(x half) + szT(z half, silu, transposed) = xn @ W_in^T + b_in
        win_kernel<<<dim3(1024 / 64, 2048 / 64), 256, 0, stream>>>(
            xn_bf, Wi_bf + (size_t)i * 2 * D_INNER * D_MODEL,
            b_in + i * 2 * D_INNER, xz, szT);

        // conv+silu fused with W_x GEMM: uT + xdbcT
        wx_conv_kernel<<<BL / 16, 256, 0, stream>>>(
            xz, conv_w + i * D_INNER * 4,
            Wx_bf + (size_t)i * 48 * D_INNER, uT, xdbcT);

        // scan with in-scan delta
        scan_kernel<<<512, 1024, 0, stream>>>(
            xdbcT, uT, szT,
            dt_w + (size_t)i * D_INNER * DT_RANK, dt_b + i * D_INNER,
            A_log + (size_t)i * D_INNER * D_STATE, Dv + i * D_INNER, y_bf);

        // out = xcur + y @ W_out^T + b_out  (M=2048, N=256, K=512)
        gemm_wout<2, 2, 2, 2><<<dim3(256 / 64, 2048 / 64), 256, 0, stream>>>(
            y_bf, D_INNER, Wo_bf + (size_t)i * D_MODEL * D_INNER, D_INNER,
            b_out + i * D_MODEL, xcur, D_MODEL, out, D_MODEL, D_INNER);
    }
}